// Round 2
// baseline (1344.278 us; speedup 1.0000x reference)
//
#include <hip/hip_runtime.h>
#include <cstdint>
#include <cstddef>

typedef unsigned short u16t;
typedef __attribute__((ext_vector_type(8))) short bf16x8;  // 8 bf16 in 4 VGPRs
typedef __attribute__((ext_vector_type(4))) float f32x4;

#define NNODES 50000
#define NEDGES 800000
#define NP 50176   // 196 * 256, padded node rows

#define MFMA(a, b, c) __builtin_amdgcn_mfma_f32_16x16x32_bf16((a), (b), (c), 0, 0, 0)

__device__ inline float b2f(short s) {
    union { float f; unsigned int u; } c;
    c.u = ((unsigned int)(unsigned short)s) << 16;
    return c.f;
}
__device__ inline short f2b(float f) {
    union { float f; unsigned int u; } c; c.f = f;
    unsigned int u = c.u;
    unsigned int r = (u + 0x7FFFu + ((u >> 16) & 1u)) >> 16;  // RNE
    return (short)(unsigned short)r;
}
__device__ inline f32x4 zero4() { f32x4 z = {0.f, 0.f, 0.f, 0.f}; return z; }

// load 8 consecutive f32 and round to bf16x8 (A/B fragment builder)
__device__ inline bf16x8 ld8f(const float* p) {
    float4 a = *(const float4*)p;
    float4 b = *(const float4*)(p + 4);
    bf16x8 r;
    r[0] = f2b(a.x); r[1] = f2b(a.y); r[2] = f2b(a.z); r[3] = f2b(a.w);
    r[4] = f2b(b.x); r[5] = f2b(b.y); r[6] = f2b(b.z); r[7] = f2b(b.w);
    return r;
}

__device__ inline void atomicMaxF(float* addr, float v) {
    if (v >= 0.f) atomicMax((int*)addr, __float_as_int(v));
    else          atomicMin((unsigned int*)addr, (unsigned int)__float_as_int(v));
}

__device__ inline float gelu_f(float x) {
    // tanh-approx GELU (JAX default)
    float u = 0.7978845608028654f * (x + 0.044715f * x * x * x);
    float e = __expf(2.f * u);
    return 0.5f * x * (2.f - 2.f / (e + 1.f));
}

// ---------------- K0: init accumulators ----------------
__global__ void k_init(float* __restrict__ msg, float* __restrict__ pooled,
                       float* __restrict__ m_n, float* __restrict__ m_e,
                       float* __restrict__ d_n, float* __restrict__ d_e) {
    int i = blockIdx.x * 256 + threadIdx.x;
    if (i < NP * 64) { msg[i] = 0.f; pooled[i] = 0.f; }
    if (i < NP * 4)  { m_n[i] = -1e30f; m_e[i] = -1e30f; d_n[i] = 0.f; d_e[i] = 0.f; }
}

// ---------------- K1: node projections qn,kn,vn,nWn = nodes @ {Wq_n,Wk_n,Wv_n,Wn_e} ----------------
__global__ __launch_bounds__(256) void k_node_proj(
        const float* __restrict__ nodes,
        const float* __restrict__ Wq, const float* __restrict__ Wk,
        const float* __restrict__ Wv, const float* __restrict__ Wn,
        float* __restrict__ qn, float* __restrict__ kn,
        float* __restrict__ vn, float* __restrict__ nWn) {
    __shared__ __align__(16) u16t wt[256 * 72];   // transposed: wt[n][k], stride 72
    {
        const float* Ws[4] = {Wq, Wk, Wv, Wn};
        for (int g = 0; g < 4; ++g) {
            const float* W = Ws[g];
            u16t* dst = wt + g * 64 * 72;
            for (int idx = threadIdx.x; idx < 4096; idx += 256) {
                int n = idx & 63, k = idx >> 6;
                dst[n * 72 + k] = (u16t)f2b(W[idx]);
            }
        }
    }
    __syncthreads();
    int l = threadIdx.x & 63, w = threadIdx.x >> 6;
    int q = l >> 4, c = l & 15;
    int r0 = blockIdx.x * 256 + w * 64;

    bf16x8 A[4][2];
#pragma unroll
    for (int st = 0; st < 4; ++st) {
        int row = r0 + st * 16 + c;
        if (row >= NNODES) row = NNODES - 1;
#pragma unroll
        for (int ks = 0; ks < 2; ++ks)
            A[st][ks] = ld8f(nodes + (size_t)row * 64 + ks * 32 + q * 8);
    }
    float* outs[4] = {qn, kn, vn, nWn};
    for (int cg = 0; cg < 4; ++cg) {
        bf16x8 B[2][4];
#pragma unroll
        for (int ks = 0; ks < 2; ++ks)
#pragma unroll
            for (int t = 0; t < 4; ++t)
                B[ks][t] = *(const bf16x8*)(wt + (cg * 64 + t * 16 + c) * 72 + ks * 32 + q * 8);
        float scale = (cg == 0) ? 0.25f : 1.0f;   // fold 1/sqrt(16) into q
        float* out = outs[cg];
#pragma unroll
        for (int st = 0; st < 4; ++st) {
            f32x4 acc[4];
#pragma unroll
            for (int t = 0; t < 4; ++t) acc[t] = zero4();
#pragma unroll
            for (int ks = 0; ks < 2; ++ks)
#pragma unroll
                for (int t = 0; t < 4; ++t)
                    acc[t] = MFMA(A[st][ks], B[ks][t], acc[t]);
#pragma unroll
            for (int r = 0; r < 4; ++r) {
                int row = r0 + st * 16 + q * 4 + r;
                if (row < NNODES) {
#pragma unroll
                    for (int t = 0; t < 4; ++t)
                        out[(size_t)row * 64 + t * 16 + c] = acc[t][r] * scale;
                }
            }
        }
    }
}

// ---------------- K2: edge scores (node-attn + edge-attn) ----------------
__global__ __launch_bounds__(256) void k_edge_scores(
        const float* __restrict__ edges, const int* __restrict__ eidx,
        const float* __restrict__ WeN, const float* __restrict__ WqE, const float* __restrict__ WkE,
        const float* __restrict__ qn, const float* __restrict__ kn, const float* __restrict__ nWn,
        float* __restrict__ s_n, float* __restrict__ s_e,
        float* __restrict__ m_n, float* __restrict__ m_e) {
    __shared__ __align__(16) u16t wt[192 * 72];
    {
        const float* Ws[3] = {WeN, WqE, WkE};
        for (int g = 0; g < 3; ++g) {
            const float* W = Ws[g];
            u16t* dst = wt + g * 64 * 72;
            for (int idx = threadIdx.x; idx < 4096; idx += 256) {
                int n = idx & 63, k = idx >> 6;
                dst[n * 72 + k] = (u16t)f2b(W[idx]);
            }
        }
    }
    __syncthreads();
    int l = threadIdx.x & 63, w = threadIdx.x >> 6;
    int q = l >> 4, c = l & 15;
    int e0 = blockIdx.x * 256 + w * 64;

    bf16x8 B[3][2][4];
#pragma unroll
    for (int g = 0; g < 3; ++g)
#pragma unroll
        for (int ks = 0; ks < 2; ++ks)
#pragma unroll
            for (int t = 0; t < 4; ++t)
                B[g][ks][t] = *(const bf16x8*)(wt + (g * 64 + t * 16 + c) * 72 + ks * 32 + q * 8);

    for (int st = 0; st < 4; ++st) {
        int em = e0 + st * 16 + c;
        bf16x8 A0 = ld8f(edges + (size_t)em * 64 + q * 8);
        bf16x8 A1 = ld8f(edges + (size_t)em * 64 + 32 + q * 8);
        f32x4 aWe[4], aQe[4], aKe[4];
#pragma unroll
        for (int t = 0; t < 4; ++t) { aWe[t] = zero4(); aQe[t] = zero4(); aKe[t] = zero4(); }
#pragma unroll
        for (int t = 0; t < 4; ++t) {
            aWe[t] = MFMA(A0, B[0][0][t], aWe[t]); aWe[t] = MFMA(A1, B[0][1][t], aWe[t]);
            aQe[t] = MFMA(A0, B[1][0][t], aQe[t]); aQe[t] = MFMA(A1, B[1][1][t], aQe[t]);
            aKe[t] = MFMA(A0, B[2][0][t], aKe[t]); aKe[t] = MFMA(A1, B[2][1][t], aKe[t]);
        }
#pragma unroll
        for (int r = 0; r < 4; ++r) {
            int e = e0 + st * 16 + q * 4 + r;
            int sr = eidx[e], tg = eidx[NEDGES + e];
#pragma unroll
            for (int t = 0; t < 4; ++t) {
                int col = t * 16 + c;
                float pn = qn[(size_t)tg * 64 + col] * (kn[(size_t)sr * 64 + col] + aWe[t][r]);
                float pe = aQe[t][r] * (aKe[t][r] + nWn[(size_t)sr * 64 + col]) * 0.25f;
#pragma unroll
                for (int m = 1; m < 16; m <<= 1) {
                    pn += __shfl_xor(pn, m);
                    pe += __shfl_xor(pe, m);
                }
                if (c == 0) {
                    s_n[(size_t)e * 4 + t] = pn;
                    s_e[(size_t)e * 4 + t] = pe;
                    atomicMaxF(&m_n[tg * 4 + t], pn);
                    atomicMaxF(&m_e[sr * 4 + t], pe);
                }
            }
        }
    }
}

// ---------------- K3: exp + denominators ----------------
__global__ __launch_bounds__(256) void k_softmax_den(
        const int* __restrict__ eidx,
        float* __restrict__ s_n, float* __restrict__ s_e,
        const float* __restrict__ m_n, const float* __restrict__ m_e,
        float* __restrict__ d_n, float* __restrict__ d_e) {
    int i = blockIdx.x * 256 + threadIdx.x;   // i < E*4 exactly
    int e = i >> 2, h = i & 3;
    int sr = eidx[e], tg = eidx[NEDGES + e];
    float exn = __expf(s_n[i] - m_n[tg * 4 + h]);
    s_n[i] = exn;
    unsafeAtomicAdd(&d_n[tg * 4 + h], exn);
    float exe = __expf(s_e[i] - m_e[sr * 4 + h]);
    s_e[i] = exe;
    unsafeAtomicAdd(&d_e[sr * 4 + h], exe);
}

// ---------------- K4: node-attention scatter: msg[tgt] += a_n * vn[src] ----------------
__global__ __launch_bounds__(256) void k_node_scatter(
        const int* __restrict__ eidx, const float* __restrict__ s_n,
        const float* __restrict__ d_n, const float* __restrict__ vn,
        float* __restrict__ msg) {
    long long t = (long long)blockIdx.x * 256 + threadIdx.x;
    int e = (int)(t >> 6), j = (int)(t & 63);
    int sr = eidx[e], tg = eidx[NEDGES + e];
    int h = j >> 4;
    float a = s_n[(size_t)e * 4 + h] / (d_n[tg * 4 + h] + 1e-9f);
    unsafeAtomicAdd(&msg[(size_t)tg * 64 + j], a * vn[(size_t)sr * 64 + j]);
}

// ---------------- K5: edge-attention: ve = edges@Wv_e (MFMA), pooled[src] += a_e * ve ----------------
__global__ __launch_bounds__(256) void k_edge_scatter(
        const float* __restrict__ edges, const int* __restrict__ eidx,
        const float* __restrict__ WvE,
        const float* __restrict__ s_e, const float* __restrict__ d_e,
        float* __restrict__ pooled) {
    __shared__ __align__(16) u16t wt[64 * 72];
    for (int idx = threadIdx.x; idx < 4096; idx += 256) {
        int n = idx & 63, k = idx >> 6;
        wt[n * 72 + k] = (u16t)f2b(WvE[idx]);
    }
    __syncthreads();
    int l = threadIdx.x & 63, w = threadIdx.x >> 6;
    int q = l >> 4, c = l & 15;
    int e0 = blockIdx.x * 256 + w * 64;
    bf16x8 B[2][4];
#pragma unroll
    for (int ks = 0; ks < 2; ++ks)
#pragma unroll
        for (int t = 0; t < 4; ++t)
            B[ks][t] = *(const bf16x8*)(wt + (t * 16 + c) * 72 + ks * 32 + q * 8);
    for (int st = 0; st < 4; ++st) {
        int em = e0 + st * 16 + c;
        bf16x8 A0 = ld8f(edges + (size_t)em * 64 + q * 8);
        bf16x8 A1 = ld8f(edges + (size_t)em * 64 + 32 + q * 8);
        f32x4 acc[4];
#pragma unroll
        for (int t = 0; t < 4; ++t) acc[t] = zero4();
#pragma unroll
        for (int t = 0; t < 4; ++t) {
            acc[t] = MFMA(A0, B[0][t], acc[t]);
            acc[t] = MFMA(A1, B[1][t], acc[t]);
        }
#pragma unroll
        for (int r = 0; r < 4; ++r) {
            int e = e0 + st * 16 + q * 4 + r;
            int sr = eidx[e];
#pragma unroll
            for (int t = 0; t < 4; ++t) {
                float a = s_e[(size_t)e * 4 + t] / (d_e[sr * 4 + t] + 1e-9f);
                unsafeAtomicAdd(&pooled[(size_t)sr * 64 + t * 16 + c], a * acc[t][r]);
            }
        }
    }
}

// ---------------- K6: node update GEMM: out(bf16) = Ain @ W (+ base) ----------------
__global__ __launch_bounds__(256) void k_node_update(
        const float* __restrict__ Ain, const float* __restrict__ W,
        const float* __restrict__ base, u16t* __restrict__ out) {
    __shared__ __align__(16) u16t wt[64 * 72];
    for (int idx = threadIdx.x; idx < 4096; idx += 256) {
        int n = idx & 63, k = idx >> 6;
        wt[n * 72 + k] = (u16t)f2b(W[idx]);
    }
    __syncthreads();
    int l = threadIdx.x & 63, w = threadIdx.x >> 6;
    int q = l >> 4, c = l & 15;
    int r0 = blockIdx.x * 256 + w * 64;
    bf16x8 B[2][4];
#pragma unroll
    for (int ks = 0; ks < 2; ++ks)
#pragma unroll
        for (int t = 0; t < 4; ++t)
            B[ks][t] = *(const bf16x8*)(wt + (t * 16 + c) * 72 + ks * 32 + q * 8);
    for (int st = 0; st < 4; ++st) {
        int row = r0 + st * 16 + c;
        if (row >= NNODES) row = NNODES - 1;
        bf16x8 A[2];
#pragma unroll
        for (int ks = 0; ks < 2; ++ks)
            A[ks] = ld8f(Ain + (size_t)row * 64 + ks * 32 + q * 8);
        f32x4 acc[4];
#pragma unroll
        for (int t = 0; t < 4; ++t) acc[t] = zero4();
#pragma unroll
        for (int t = 0; t < 4; ++t) {
            acc[t] = MFMA(A[0], B[0][t], acc[t]);
            acc[t] = MFMA(A[1], B[1][t], acc[t]);
        }
#pragma unroll
        for (int r = 0; r < 4; ++r) {
            int rw = r0 + st * 16 + q * 4 + r;
            if (rw < NNODES) {
#pragma unroll
                for (int t = 0; t < 4; ++t) {
                    int col = t * 16 + c;
                    float v = acc[t][r];
                    if (base) v += base[(size_t)rw * 64 + col];
                    out[(size_t)rw * 64 + col] = (u16t)f2b(v);
                }
            }
        }
    }
}

// ---------------- K7: classifier: gather+concat -> W1 -> GELU -> W2 -> out(f32) ----------------
__global__ __launch_bounds__(256) void k_classifier(
        const float* __restrict__ edges, const int* __restrict__ eidx,
        const u16t* __restrict__ newN, const u16t* __restrict__ pWo,
        const float* __restrict__ W1, const float* __restrict__ b1,
        const float* __restrict__ W2, const float* __restrict__ b2,
        float* __restrict__ out) {
    __shared__ __align__(16) u16t wt1[64 * 200];     // Wt1[n][k], n<64, k<192, stride 200
    __shared__ __align__(16) u16t wt2[48 * 72];      // Wt2[n][k], n<48 (pad 40->48 zeros), k<64
    __shared__ __align__(16) u16t hbuf[4][16 * 72];  // per-wave h tile, row stride 72
    for (int idx = threadIdx.x; idx < 192 * 64; idx += 256) {
        int n = idx & 63, k = idx >> 6;
        wt1[n * 200 + k] = (u16t)f2b(W1[idx]);
    }
    for (int idx = threadIdx.x; idx < 48 * 64; idx += 256) {
        int n = idx % 48, k = idx / 48;
        wt2[n * 72 + k] = (n < 40) ? (u16t)f2b(W2[k * 40 + n]) : (u16t)0;
    }
    __syncthreads();
    int l = threadIdx.x & 63, w = threadIdx.x >> 6;
    int q = l >> 4, c = l & 15;
    int e0 = blockIdx.x * 256 + w * 64;

    bf16x8 B1[6][4];
#pragma unroll
    for (int ks = 0; ks < 6; ++ks)
#pragma unroll
        for (int t = 0; t < 4; ++t)
            B1[ks][t] = *(const bf16x8*)(wt1 + (t * 16 + c) * 200 + ks * 32 + q * 8);
    bf16x8 B2[2][3];
#pragma unroll
    for (int ks = 0; ks < 2; ++ks)
#pragma unroll
        for (int t = 0; t < 3; ++t)
            B2[ks][t] = *(const bf16x8*)(wt2 + (t * 16 + c) * 72 + ks * 32 + q * 8);

    for (int st = 0; st < 4; ++st) {
        int em = e0 + st * 16 + c;
        int srm = eidx[em], tgm = eidx[NEDGES + em];
        bf16x8 A[6];
#pragma unroll
        for (int ks = 0; ks < 2; ++ks) {
            A[ks]     = *(const bf16x8*)(newN + (size_t)srm * 64 + ks * 32 + q * 8);
            A[2 + ks] = *(const bf16x8*)(newN + (size_t)tgm * 64 + ks * 32 + q * 8);
            const float* ep = edges + (size_t)em * 64 + ks * 32 + q * 8;
            float4 x0 = *(const float4*)ep;
            float4 x1 = *(const float4*)(ep + 4);
            bf16x8 y = *(const bf16x8*)(pWo + (size_t)srm * 64 + ks * 32 + q * 8);
            bf16x8 z;
            z[0] = f2b(x0.x + b2f(y[0])); z[1] = f2b(x0.y + b2f(y[1]));
            z[2] = f2b(x0.z + b2f(y[2])); z[3] = f2b(x0.w + b2f(y[3]));
            z[4] = f2b(x1.x + b2f(y[4])); z[5] = f2b(x1.y + b2f(y[5]));
            z[6] = f2b(x1.z + b2f(y[6])); z[7] = f2b(x1.w + b2f(y[7]));
            A[4 + ks] = z;
        }
        f32x4 acc1[4];
#pragma unroll
        for (int t = 0; t < 4; ++t) acc1[t] = zero4();
#pragma unroll
        for (int ks = 0; ks < 6; ++ks)
#pragma unroll
            for (int t = 0; t < 4; ++t)
                acc1[t] = MFMA(A[ks], B1[ks][t], acc1[t]);
        // bias + GELU -> hbuf (bf16, A-layout rows)
#pragma unroll
        for (int t = 0; t < 4; ++t) {
            float bb = b1[t * 16 + c];
#pragma unroll
            for (int r = 0; r < 4; ++r) {
                float x = acc1[t][r] + bb;
                hbuf[w][(q * 4 + r) * 72 + t * 16 + c] = (u16t)f2b(gelu_f(x));
            }
        }
        __syncthreads();
        bf16x8 A2[2];
#pragma unroll
        for (int ks = 0; ks < 2; ++ks)
            A2[ks] = *(const bf16x8*)(&hbuf[w][c * 72 + ks * 32 + q * 8]);
        f32x4 acc2[3];
#pragma unroll
        for (int t = 0; t < 3; ++t) acc2[t] = zero4();
#pragma unroll
        for (int ks = 0; ks < 2; ++ks)
#pragma unroll
            for (int t = 0; t < 3; ++t)
                acc2[t] = MFMA(A2[ks], B2[ks][t], acc2[t]);
#pragma unroll
        for (int r = 0; r < 4; ++r) {
            int e = e0 + st * 16 + q * 4 + r;
#pragma unroll
            for (int t = 0; t < 3; ++t) {
                int col = t * 16 + c;
                if (col < 40)
                    out[(size_t)e * 40 + col] = acc2[t][r] + b2[col];
            }
        }
        __syncthreads();
    }
}

extern "C" void kernel_launch(void* const* d_in, const int* in_sizes, int n_in,
                              void* d_out, int out_size, void* d_ws, size_t ws_size,
                              hipStream_t stream) {
    if (n_in < 17) return;
    const float* nodes = (const float*)d_in[0];
    const float* edges = (const float*)d_in[1];
    const int*   eidx  = (const int*)d_in[2];
    const float* Wq_n = (const float*)d_in[3];
    const float* Wk_n = (const float*)d_in[4];
    const float* We_n = (const float*)d_in[5];
    const float* Wv_n = (const float*)d_in[6];
    const float* Wo_n = (const float*)d_in[7];
    const float* Wq_e = (const float*)d_in[8];
    const float* Wk_e = (const float*)d_in[9];
    const float* Wn_e = (const float*)d_in[10];
    const float* Wv_e = (const float*)d_in[11];
    const float* Wo_e = (const float*)d_in[12];
    const float* W1   = (const float*)d_in[13];
    const float* b1   = (const float*)d_in[14];
    const float* W2   = (const float*)d_in[15];
    const float* b2   = (const float*)d_in[16];
    float* out = (float*)d_out;

    float* ws = (float*)d_ws;
    size_t o = 0;
    float* qn  = ws + o; o += (size_t)NP * 64;
    float* kn  = ws + o; o += (size_t)NP * 64;
    float* vn  = ws + o; o += (size_t)NP * 64;
    float* nWn = ws + o; o += (size_t)NP * 64;
    float* m_n = ws + o; o += (size_t)NP * 4;
    float* m_e = ws + o; o += (size_t)NP * 4;
    float* d_n = ws + o; o += (size_t)NP * 4;
    float* d_e = ws + o; o += (size_t)NP * 4;
    float* msg    = ws + o; o += (size_t)NP * 64;
    float* pooled = ws + o; o += (size_t)NP * 64;
    float* s_n = ws + o; o += (size_t)NEDGES * 4;
    float* s_e = ws + o; o += (size_t)NEDGES * 4;
    u16t* newN = (u16t*)(ws + o); o += (size_t)NP * 32;
    u16t* pWo  = (u16t*)(ws + o); o += (size_t)NP * 32;
    if (ws_size < o * sizeof(float)) return;  // not enough scratch: fail visibly

    k_init<<<12544, 256, 0, stream>>>(msg, pooled, m_n, m_e, d_n, d_e);
    k_node_proj<<<196, 256, 0, stream>>>(nodes, Wq_n, Wk_n, Wv_n, Wn_e, qn, kn, vn, nWn);
    k_edge_scores<<<3125, 256, 0, stream>>>(edges, eidx, We_n, Wq_e, Wk_e,
                                            qn, kn, nWn, s_n, s_e, m_n, m_e);
    k_softmax_den<<<12500, 256, 0, stream>>>(eidx, s_n, s_e, m_n, m_e, d_n, d_e);
    k_node_scatter<<<200000, 256, 0, stream>>>(eidx, s_n, d_n, vn, msg);
    k_edge_scatter<<<3125, 256, 0, stream>>>(edges, eidx, Wv_e, s_e, d_e, pooled);
    k_node_update<<<196, 256, 0, stream>>>(msg, Wo_n, nodes, newN);
    k_node_update<<<196, 256, 0, stream>>>(pooled, Wo_e, nullptr, pWo);
    k_classifier<<<3125, 256, 0, stream>>>(edges, eidx, newN, pWo, W1, b1, W2, b2, out);
}

// Round 3
// 1043.619 us; speedup vs baseline: 1.2881x; 1.2881x over previous
//
#include <hip/hip_runtime.h>
#include <cstdint>
#include <cstddef>

typedef unsigned short u16t;
typedef __attribute__((ext_vector_type(8))) short bf16x8;  // 8 bf16 in 4 VGPRs
typedef __attribute__((ext_vector_type(4))) float f32x4;

#define NNODES 50000
#define NEDGES 800000
#define NP 50176   // 196 * 256, padded node rows

#define MFMA(a, b, c) __builtin_amdgcn_mfma_f32_16x16x32_bf16((a), (b), (c), 0, 0, 0)

__device__ inline float b2f(short s) {
    union { float f; unsigned int u; } c;
    c.u = ((unsigned int)(unsigned short)s) << 16;
    return c.f;
}
__device__ inline short f2b(float f) {
    union { float f; unsigned int u; } c; c.f = f;
    unsigned int u = c.u;
    unsigned int r = (u + 0x7FFFu + ((u >> 16) & 1u)) >> 16;  // RNE
    return (short)(unsigned short)r;
}
__device__ inline f32x4 zero4() { f32x4 z = {0.f, 0.f, 0.f, 0.f}; return z; }

// load 8 consecutive f32 and round to bf16x8 (A/B fragment builder)
__device__ inline bf16x8 ld8f(const float* p) {
    float4 a = *(const float4*)p;
    float4 b = *(const float4*)(p + 4);
    bf16x8 r;
    r[0] = f2b(a.x); r[1] = f2b(a.y); r[2] = f2b(a.z); r[3] = f2b(a.w);
    r[4] = f2b(b.x); r[5] = f2b(b.y); r[6] = f2b(b.z); r[7] = f2b(b.w);
    return r;
}

__device__ inline float gelu_f(float x) {
    float u = 0.7978845608028654f * (x + 0.044715f * x * x * x);
    float e = __expf(2.f * u);
    return 0.5f * x * (2.f - 2.f / (e + 1.f));
}

// ---------------- K0: init accumulators ----------------
__global__ void k_init(float* __restrict__ msg, float* __restrict__ pooled,
                       float* __restrict__ d_n, float* __restrict__ d_e) {
    int i = blockIdx.x * 256 + threadIdx.x;
    if (i < NP * 64) { msg[i] = 0.f; pooled[i] = 0.f; }
    if (i < NP * 4)  { d_n[i] = 0.f; d_e[i] = 0.f; }
}

// ---------------- K1: node projections (bf16 out): qn,kn,vn,nWn ----------------
__global__ __launch_bounds__(256) void k_node_proj(
        const float* __restrict__ nodes,
        const float* __restrict__ Wq, const float* __restrict__ Wk,
        const float* __restrict__ Wv, const float* __restrict__ Wn,
        u16t* __restrict__ qn, u16t* __restrict__ kn,
        u16t* __restrict__ vn, u16t* __restrict__ nWn) {
    __shared__ __align__(16) u16t wt[256 * 72];   // transposed: wt[n][k], stride 72
    {
        const float* Ws[4] = {Wq, Wk, Wv, Wn};
        for (int g = 0; g < 4; ++g) {
            const float* W = Ws[g];
            u16t* dst = wt + g * 64 * 72;
            for (int idx = threadIdx.x; idx < 4096; idx += 256) {
                int n = idx & 63, k = idx >> 6;
                dst[n * 72 + k] = (u16t)f2b(W[idx]);
            }
        }
    }
    __syncthreads();
    int l = threadIdx.x & 63, w = threadIdx.x >> 6;
    int q = l >> 4, c = l & 15;
    int r0 = blockIdx.x * 256 + w * 64;

    bf16x8 A[4][2];
#pragma unroll
    for (int st = 0; st < 4; ++st) {
        int row = r0 + st * 16 + c;
        if (row >= NNODES) row = NNODES - 1;
#pragma unroll
        for (int ks = 0; ks < 2; ++ks)
            A[st][ks] = ld8f(nodes + (size_t)row * 64 + ks * 32 + q * 8);
    }
    u16t* outs[4] = {qn, kn, vn, nWn};
    for (int cg = 0; cg < 4; ++cg) {
        bf16x8 B[2][4];
#pragma unroll
        for (int ks = 0; ks < 2; ++ks)
#pragma unroll
            for (int t = 0; t < 4; ++t)
                B[ks][t] = *(const bf16x8*)(wt + (cg * 64 + t * 16 + c) * 72 + ks * 32 + q * 8);
        float scale = (cg == 0) ? 0.25f : 1.0f;   // fold 1/sqrt(16) into q
        u16t* out = outs[cg];
#pragma unroll
        for (int st = 0; st < 4; ++st) {
            f32x4 acc[4];
#pragma unroll
            for (int t = 0; t < 4; ++t) acc[t] = zero4();
#pragma unroll
            for (int ks = 0; ks < 2; ++ks)
#pragma unroll
                for (int t = 0; t < 4; ++t)
                    acc[t] = MFMA(A[st][ks], B[ks][t], acc[t]);
#pragma unroll
            for (int r = 0; r < 4; ++r) {
                int row = r0 + st * 16 + q * 4 + r;
                if (row < NNODES) {
#pragma unroll
                    for (int t = 0; t < 4; ++t)
                        out[(size_t)row * 64 + t * 16 + c] = (u16t)f2b(acc[t][r] * scale);
                }
            }
        }
    }
}

// ---------------- K2: edge scores -> exp + den atomics (no max pass) ----------------
__global__ __launch_bounds__(256) void k_edge_scores(
        const float* __restrict__ edges, const int* __restrict__ eidx,
        const float* __restrict__ WeN, const float* __restrict__ WqE, const float* __restrict__ WkE,
        const u16t* __restrict__ qn, const u16t* __restrict__ kn, const u16t* __restrict__ nWn,
        float* __restrict__ s_n, float* __restrict__ s_e,
        float* __restrict__ d_n, float* __restrict__ d_e) {
    __shared__ __align__(16) u16t wt[192 * 72];
    for (int idx = threadIdx.x; idx < 4096; idx += 256) {
        int n = idx & 63, k = idx >> 6;
        wt[n * 72 + k]         = (u16t)f2b(WeN[idx]);
        wt[(64 + n) * 72 + k]  = (u16t)f2b(0.25f * WqE[idx]);  // fold 1/sqrt(16)
        wt[(128 + n) * 72 + k] = (u16t)f2b(WkE[idx]);
    }
    __syncthreads();
    int l = threadIdx.x & 63, w = threadIdx.x >> 6;
    int q = l >> 4, c = l & 15;
    int rsel = c >> 2, tsel = c & 3;
    int e0 = blockIdx.x * 256 + w * 64;

    for (int st = 0; st < 4; ++st) {
        int eA = e0 + st * 16 + c;
        bf16x8 A0 = ld8f(edges + (size_t)eA * 64 + q * 8);
        bf16x8 A1 = ld8f(edges + (size_t)eA * 64 + 32 + q * 8);
        f32x4 aWe[4], aQe[4], aKe[4];
#pragma unroll
        for (int t = 0; t < 4; ++t) { aWe[t] = zero4(); aQe[t] = zero4(); aKe[t] = zero4(); }
#pragma unroll
        for (int t = 0; t < 4; ++t) {
            const u16t* b0 = wt + (t * 16 + c) * 72;         // We_n^T
            const u16t* b1 = wt + (64 + t * 16 + c) * 72;    // Wq_e^T (scaled)
            const u16t* b2 = wt + (128 + t * 16 + c) * 72;   // Wk_e^T
            aWe[t] = MFMA(A0, *(const bf16x8*)(b0 + q * 8), aWe[t]);
            aWe[t] = MFMA(A1, *(const bf16x8*)(b0 + 32 + q * 8), aWe[t]);
            aQe[t] = MFMA(A0, *(const bf16x8*)(b1 + q * 8), aQe[t]);
            aQe[t] = MFMA(A1, *(const bf16x8*)(b1 + 32 + q * 8), aQe[t]);
            aKe[t] = MFMA(A0, *(const bf16x8*)(b2 + q * 8), aKe[t]);
            aKe[t] = MFMA(A1, *(const bf16x8*)(b2 + 32 + q * 8), aKe[t]);
        }
        float kept_n = 0.f, kept_e = 0.f;
#pragma unroll
        for (int r = 0; r < 4; ++r) {
            int e = e0 + st * 16 + q * 4 + r;
            int sr = eidx[e], tg = eidx[NEDGES + e];
#pragma unroll
            for (int t = 0; t < 4; ++t) {
                int col = t * 16 + c;
                float pn = b2f((short)qn[(size_t)tg * 64 + col]) *
                           (b2f((short)kn[(size_t)sr * 64 + col]) + aWe[t][r]);
                float pe = aQe[t][r] * (aKe[t][r] + b2f((short)nWn[(size_t)sr * 64 + col]));
#pragma unroll
                for (int m = 1; m < 16; m <<= 1) {
                    pn += __shfl_xor(pn, m);
                    pe += __shfl_xor(pe, m);
                }
                if (r == rsel && t == tsel) { kept_n = pn; kept_e = pe; }
            }
        }
        // lane l owns edge e0+st*16+(l>>2), head l&3
        int eL = e0 + st * 16 + (l >> 2);
        int srL = eidx[eL], tgL = eidx[NEDGES + eL];
        float exn = __expf(kept_n), exe = __expf(kept_e);
        size_t sbase = (size_t)(e0 + st * 16) * 4;
        s_n[sbase + l] = exn;
        s_e[sbase + l] = exe;
        unsafeAtomicAdd(&d_n[tgL * 4 + tsel], exn);
        unsafeAtomicAdd(&d_e[srL * 4 + tsel], exe);
    }
}

// ---------------- K3: invert denominators ----------------
__global__ void k_invden(float* __restrict__ d_n, float* __restrict__ d_e) {
    int i = blockIdx.x * 256 + threadIdx.x;
    if (i < NNODES * 4) {
        d_n[i] = 1.f / (d_n[i] + 1e-9f);
        d_e[i] = 1.f / (d_e[i] + 1e-9f);
    }
}

// ---------------- K4: node-attention scatter: msg[tgt] += a_n * vn[src] ----------------
__global__ __launch_bounds__(256) void k_node_scatter(
        const int* __restrict__ eidx, const float* __restrict__ s_n,
        const float* __restrict__ d_n, const u16t* __restrict__ vn,
        float* __restrict__ msg) {
    long long t = (long long)blockIdx.x * 256 + threadIdx.x;
    int e = (int)(t >> 6), j = (int)(t & 63);
    int sr = eidx[e], tg = eidx[NEDGES + e];
    int h = j >> 4;
    float a = s_n[(size_t)e * 4 + h] * d_n[tg * 4 + h];
    unsafeAtomicAdd(&msg[(size_t)tg * 64 + j], a * b2f((short)vn[(size_t)sr * 64 + j]));
}

// ---------------- K5: edge-attention: ve = edges@Wv_e (MFMA), pooled[src] += a_e * ve ----------------
__global__ __launch_bounds__(256) void k_edge_scatter(
        const float* __restrict__ edges, const int* __restrict__ eidx,
        const float* __restrict__ WvE,
        const float* __restrict__ s_e, const float* __restrict__ d_e,
        float* __restrict__ pooled) {
    __shared__ __align__(16) u16t wt[64 * 72];
    for (int idx = threadIdx.x; idx < 4096; idx += 256) {
        int n = idx & 63, k = idx >> 6;
        wt[n * 72 + k] = (u16t)f2b(WvE[idx]);
    }
    __syncthreads();
    int l = threadIdx.x & 63, w = threadIdx.x >> 6;
    int q = l >> 4, c = l & 15;
    int e0 = blockIdx.x * 256 + w * 64;
    for (int st = 0; st < 4; ++st) {
        int em = e0 + st * 16 + c;
        bf16x8 A0 = ld8f(edges + (size_t)em * 64 + q * 8);
        bf16x8 A1 = ld8f(edges + (size_t)em * 64 + 32 + q * 8);
        f32x4 acc[4];
#pragma unroll
        for (int t = 0; t < 4; ++t) acc[t] = zero4();
#pragma unroll
        for (int t = 0; t < 4; ++t) {
            const u16t* bp = wt + (t * 16 + c) * 72;
            acc[t] = MFMA(A0, *(const bf16x8*)(bp + q * 8), acc[t]);
            acc[t] = MFMA(A1, *(const bf16x8*)(bp + 32 + q * 8), acc[t]);
        }
#pragma unroll
        for (int r = 0; r < 4; ++r) {
            int e = e0 + st * 16 + q * 4 + r;
            int sr = eidx[e];
#pragma unroll
            for (int t = 0; t < 4; ++t) {
                float a = s_e[(size_t)e * 4 + t] * d_e[sr * 4 + t];
                unsafeAtomicAdd(&pooled[(size_t)sr * 64 + t * 16 + c], a * acc[t][r]);
            }
        }
    }
}

// ---------------- K6: node update GEMM: out(bf16) = Ain @ W (+ base) ----------------
__global__ __launch_bounds__(256) void k_node_update(
        const float* __restrict__ Ain, const float* __restrict__ W,
        const float* __restrict__ base, u16t* __restrict__ out) {
    __shared__ __align__(16) u16t wt[64 * 72];
    for (int idx = threadIdx.x; idx < 4096; idx += 256) {
        int n = idx & 63, k = idx >> 6;
        wt[n * 72 + k] = (u16t)f2b(W[idx]);
    }
    __syncthreads();
    int l = threadIdx.x & 63, w = threadIdx.x >> 6;
    int q = l >> 4, c = l & 15;
    int r0 = blockIdx.x * 256 + w * 64;
    bf16x8 B[2][4];
#pragma unroll
    for (int ks = 0; ks < 2; ++ks)
#pragma unroll
        for (int t = 0; t < 4; ++t)
            B[ks][t] = *(const bf16x8*)(wt + (t * 16 + c) * 72 + ks * 32 + q * 8);
    for (int st = 0; st < 4; ++st) {
        int row = r0 + st * 16 + c;
        if (row >= NNODES) row = NNODES - 1;
        bf16x8 A[2];
#pragma unroll
        for (int ks = 0; ks < 2; ++ks)
            A[ks] = ld8f(Ain + (size_t)row * 64 + ks * 32 + q * 8);
        f32x4 acc[4];
#pragma unroll
        for (int t = 0; t < 4; ++t) acc[t] = zero4();
#pragma unroll
        for (int t = 0; t < 4; ++t) {
            acc[t] = MFMA(A[0], B[0][t], acc[t]);
            acc[t] = MFMA(A[1], B[1][t], acc[t]);
        }
#pragma unroll
        for (int r = 0; r < 4; ++r) {
            int rw = r0 + st * 16 + q * 4 + r;
            if (rw < NNODES) {
#pragma unroll
                for (int t = 0; t < 4; ++t) {
                    int col = t * 16 + c;
                    float v = acc[t][r];
                    if (base) v += base[(size_t)rw * 64 + col];
                    out[(size_t)rw * 64 + col] = (u16t)f2b(v);
                }
            }
        }
    }
}

// ---------------- K7: classifier: gather+concat -> W1 -> GELU -> W2 -> out(f32) ----------------
__global__ __launch_bounds__(256) void k_classifier(
        const float* __restrict__ edges, const int* __restrict__ eidx,
        const u16t* __restrict__ newN, const u16t* __restrict__ pWo,
        const float* __restrict__ W1, const float* __restrict__ b1,
        const float* __restrict__ W2, const float* __restrict__ b2,
        float* __restrict__ out) {
    __shared__ __align__(16) u16t wt1[64 * 200];     // Wt1[n][k], n<64, k<192, stride 200
    __shared__ __align__(16) u16t wt2[48 * 72];      // Wt2[n][k], n<48 (pad 40->48 zeros), k<64
    __shared__ __align__(16) u16t hbuf[4][16 * 72];  // per-wave h tile, row stride 72
    for (int idx = threadIdx.x; idx < 192 * 64; idx += 256) {
        int n = idx & 63, k = idx >> 6;
        wt1[n * 200 + k] = (u16t)f2b(W1[idx]);
    }
    for (int idx = threadIdx.x; idx < 48 * 64; idx += 256) {
        int n = idx % 48, k = idx / 48;
        wt2[n * 72 + k] = (n < 40) ? (u16t)f2b(W2[k * 40 + n]) : (u16t)0;
    }
    __syncthreads();
    int l = threadIdx.x & 63, w = threadIdx.x >> 6;
    int q = l >> 4, c = l & 15;
    int e0 = blockIdx.x * 256 + w * 64;

    bf16x8 B1[6][4];
#pragma unroll
    for (int ks = 0; ks < 6; ++ks)
#pragma unroll
        for (int t = 0; t < 4; ++t)
            B1[ks][t] = *(const bf16x8*)(wt1 + (t * 16 + c) * 200 + ks * 32 + q * 8);
    bf16x8 B2[2][3];
#pragma unroll
    for (int ks = 0; ks < 2; ++ks)
#pragma unroll
        for (int t = 0; t < 3; ++t)
            B2[ks][t] = *(const bf16x8*)(wt2 + (t * 16 + c) * 72 + ks * 32 + q * 8);

    for (int st = 0; st < 4; ++st) {
        int em = e0 + st * 16 + c;
        int srm = eidx[em], tgm = eidx[NEDGES + em];
        bf16x8 A[6];
#pragma unroll
        for (int ks = 0; ks < 2; ++ks) {
            A[ks]     = *(const bf16x8*)(newN + (size_t)srm * 64 + ks * 32 + q * 8);
            A[2 + ks] = *(const bf16x8*)(newN + (size_t)tgm * 64 + ks * 32 + q * 8);
            const float* ep = edges + (size_t)em * 64 + ks * 32 + q * 8;
            float4 x0 = *(const float4*)ep;
            float4 x1 = *(const float4*)(ep + 4);
            bf16x8 y = *(const bf16x8*)(pWo + (size_t)srm * 64 + ks * 32 + q * 8);
            bf16x8 z;
            z[0] = f2b(x0.x + b2f(y[0])); z[1] = f2b(x0.y + b2f(y[1]));
            z[2] = f2b(x0.z + b2f(y[2])); z[3] = f2b(x0.w + b2f(y[3]));
            z[4] = f2b(x1.x + b2f(y[4])); z[5] = f2b(x1.y + b2f(y[5]));
            z[6] = f2b(x1.z + b2f(y[6])); z[7] = f2b(x1.w + b2f(y[7]));
            A[4 + ks] = z;
        }
        f32x4 acc1[4];
#pragma unroll
        for (int t = 0; t < 4; ++t) acc1[t] = zero4();
#pragma unroll
        for (int ks = 0; ks < 6; ++ks)
#pragma unroll
            for (int t = 0; t < 4; ++t)
                acc1[t] = MFMA(A[ks], B1[ks][t], acc1[t]);
        // bias + GELU -> hbuf (bf16, A-layout rows); hbuf is wave-private, no barrier needed
#pragma unroll
        for (int t = 0; t < 4; ++t) {
            float bb = b1[t * 16 + c];
#pragma unroll
            for (int r = 0; r < 4; ++r) {
                float x = acc1[t][r] + bb;
                hbuf[w][(q * 4 + r) * 72 + t * 16 + c] = (u16t)f2b(gelu_f(x));
            }
        }
        bf16x8 A2[2];
#pragma unroll
        for (int ks = 0; ks < 2; ++ks)
            A2[ks] = *(const bf16x8*)(&hbuf[w][c * 72 + ks * 32 + q * 8]);
        f32x4 acc2[3];
#pragma unroll
        for (int t = 0; t < 3; ++t) acc2[t] = zero4();
#pragma unroll
        for (int ks = 0; ks < 2; ++ks)
#pragma unroll
            for (int t = 0; t < 3; ++t)
                acc2[t] = MFMA(A2[ks], B2[ks][t], acc2[t]);
#pragma unroll
        for (int r = 0; r < 4; ++r) {
            int e = e0 + st * 16 + q * 4 + r;
#pragma unroll
            for (int t = 0; t < 3; ++t) {
                int col = t * 16 + c;
                if (col < 40)
                    out[(size_t)e * 40 + col] = acc2[t][r] + b2[col];
            }
        }
    }
}

extern "C" void kernel_launch(void* const* d_in, const int* in_sizes, int n_in,
                              void* d_out, int out_size, void* d_ws, size_t ws_size,
                              hipStream_t stream) {
    if (n_in < 17) return;
    const float* nodes = (const float*)d_in[0];
    const float* edges = (const float*)d_in[1];
    const int*   eidx  = (const int*)d_in[2];
    const float* Wq_n = (const float*)d_in[3];
    const float* Wk_n = (const float*)d_in[4];
    const float* We_n = (const float*)d_in[5];
    const float* Wv_n = (const float*)d_in[6];
    const float* Wo_n = (const float*)d_in[7];
    const float* Wq_e = (const float*)d_in[8];
    const float* Wk_e = (const float*)d_in[9];
    const float* Wn_e = (const float*)d_in[10];
    const float* Wv_e = (const float*)d_in[11];
    const float* Wo_e = (const float*)d_in[12];
    const float* W1   = (const float*)d_in[13];
    const float* b1   = (const float*)d_in[14];
    const float* W2   = (const float*)d_in[15];
    const float* b2   = (const float*)d_in[16];
    float* out = (float*)d_out;

    float* ws = (float*)d_ws;
    size_t o = 0;
    u16t* qn  = (u16t*)(ws + o); o += (size_t)NP * 32;
    u16t* kn  = (u16t*)(ws + o); o += (size_t)NP * 32;
    u16t* vn  = (u16t*)(ws + o); o += (size_t)NP * 32;
    u16t* nWn = (u16t*)(ws + o); o += (size_t)NP * 32;
    float* d_n = ws + o; o += (size_t)NP * 4;
    float* d_e = ws + o; o += (size_t)NP * 4;
    float* msg    = ws + o; o += (size_t)NP * 64;
    float* pooled = ws + o; o += (size_t)NP * 64;
    float* s_n = ws + o; o += (size_t)NEDGES * 4;
    float* s_e = ws + o; o += (size_t)NEDGES * 4;
    u16t* newN = (u16t*)(ws + o); o += (size_t)NP * 32;
    u16t* pWo  = (u16t*)(ws + o); o += (size_t)NP * 32;
    if (ws_size < o * sizeof(float)) return;  // not enough scratch: fail visibly

    k_init<<<12544, 256, 0, stream>>>(msg, pooled, d_n, d_e);
    k_node_proj<<<196, 256, 0, stream>>>(nodes, Wq_n, Wk_n, Wv_n, Wn_e, qn, kn, vn, nWn);
    k_edge_scores<<<3125, 256, 0, stream>>>(edges, eidx, We_n, Wq_e, Wk_e,
                                            qn, kn, nWn, s_n, s_e, d_n, d_e);
    k_invden<<<782, 256, 0, stream>>>(d_n, d_e);
    k_node_scatter<<<200000, 256, 0, stream>>>(eidx, s_n, d_n, vn, msg);
    k_edge_scatter<<<3125, 256, 0, stream>>>(edges, eidx, Wv_e, s_e, d_e, pooled);
    k_node_update<<<196, 256, 0, stream>>>(msg, Wo_n, nodes, newN);
    k_node_update<<<196, 256, 0, stream>>>(pooled, Wo_e, nullptr, pWo);
    k_classifier<<<3125, 256, 0, stream>>>(edges, eidx, newN, pWo, W1, b1, W2, b2, out);
}